// Round 4
// baseline (495.291 us; speedup 1.0000x reference)
//
#include <hip/hip_runtime.h>
#include <hip/hip_bf16.h>
#include <cstdint>

// Problem constants
#define BB 4
#define CC 512
#define CQK 64
#define HH 129
#define WW 129
#define HS 65
#define WSZ 65
#define NN 4225            // HS*WSZ
#define NP 4352            // padded N (34*128)
#define OUTSZ 34080768     // BB*CC*HH*WW
#define ESZ 17850625       // NN*NN
#define PVNT 17            // K-tiles (64) per PV block: split-K4, 4*17*64 = 4352

typedef unsigned short u16;
typedef __attribute__((ext_vector_type(8))) __bf16 bfrag;
typedef __attribute__((ext_vector_type(4))) float f4v;

__device__ inline u16 f2bf(float f) {
    union { float f; unsigned int u; } v; v.f = f;
    unsigned int u = v.u;
    return (u16)((u + 0x7FFFu + ((u >> 16) & 1u)) >> 16);
}
__device__ inline float bf2f(u16 v) {
    union { unsigned u; float f; } x; x.u = (unsigned)v << 16; return x.f;
}

// async global->LDS, 16 bytes per lane; lds dest must be wave-uniform base
__device__ __forceinline__ void gload16(const u16* g, u16* l) {
    __builtin_amdgcn_global_load_lds(
        (const __attribute__((address_space(1))) void*)g,
        (__attribute__((address_space(3))) void*)l, 16, 0, 0);
}

// ---------------- K0: cast & pack weights [640][512] bf16
__global__ __launch_bounds__(256) void cast_weights(const float* __restrict__ Wq,
                                                    const float* __restrict__ Wk,
                                                    const float* __restrict__ Wv,
                                                    u16* __restrict__ Wc) {
    int idx = blockIdx.x * 256 + threadIdx.x;
    if (idx >= 640 * 512) return;
    int o = idx >> 9, c = idx & 511;
    float v = (o < 64) ? Wq[o * 512 + c] : (o < 128) ? Wk[(o - 64) * 512 + c] : Wv[(o - 128) * 512 + c];
    Wc[idx] = f2bf(v);
}

// ---------------- K1: subsample (exact stride-2) + transpose to XsT[b][n][c] bf16
__global__ __launch_bounds__(256) void subsample_t(const float* __restrict__ x, u16* __restrict__ XsT) {
    __shared__ u16 tile[64][65];
    int nt = blockIdx.x, ct = blockIdx.y, b = blockIdx.z;
    int t = threadIdx.x;
#pragma unroll
    for (int l = 0; l < 16; ++l) {
        int e = t + l * 256;
        int ci = e >> 6, nj = e & 63;
        int n = nt * 64 + nj;
        int nc = n < (NN - 1) ? n : (NN - 1);
        int i = nc / 65, j = nc % 65;
        int c = ct * 64 + ci;
        float v = x[(((size_t)b * CC + c) * HH + 2 * i) * WW + 2 * j];
        tile[ci][nj] = f2bf(v);
    }
    __syncthreads();
#pragma unroll
    for (int l = 0; l < 16; ++l) {
        int e = t + l * 256;
        int nj = e >> 6, ci = e & 63;
        XsT[((size_t)b * NP + nt * 64 + nj) * 512 + ct * 64 + ci] = tile[ci][nj];
    }
}

// ---------------- NT GEMM (m97 structure) for QKV and energy
// MODE 0: QKV  A=Wc[640][512], B=XsT[b], out -> qkT[n][o] (o<128) / V[o-128][n], +bias, bf16
// MODE 1: energy A=qkT[b] cols0-63 (q), B=qkT[b] cols64-127 (k), K=64,
//         out -> energy fp32 + Ptil bf16 (=exp(e), col-padded 0) + per-row partial sums
template <int MODE>
__global__ __launch_bounds__(256) void gemm_nt(const u16* __restrict__ Abase,
                                               const u16* __restrict__ Bbase,
                                               int K, int lda, int ldb,
                                               float* __restrict__ outF,
                                               u16* __restrict__ out1, u16* __restrict__ out2,
                                               const float* __restrict__ bq,
                                               const float* __restrict__ bk,
                                               const float* __restrict__ bv,
                                               float* __restrict__ psums) {
    __shared__ __align__(16) u16 As[128 * 64];
    __shared__ __align__(16) u16 Bs[128 * 64];

    const int z = blockIdx.z;
    const u16* A; const u16* Bm;
    if (MODE == 0) { A = Abase;                          Bm = Bbase + (size_t)z * NP * 512; }
    if (MODE == 1) { A = Abase + (size_t)z * NP * 128;   Bm = Bbase + (size_t)z * NP * 128 + 64; }

    const size_t m0 = (size_t)blockIdx.y * 128;
    const size_t n0 = (size_t)blockIdx.x * 128;
    const u16* Ab = A + m0 * lda;
    const u16* Bb = Bm + n0 * ldb;

    const int tid = threadIdx.x;
    const int lane = tid & 63, w = tid >> 6;
    const int wr = w >> 1, wc = w & 1;
    const int frow = lane & 15, fk = (lane >> 4) * 8;

    f4v acc[4][4];
#pragma unroll
    for (int i = 0; i < 4; ++i)
#pragma unroll
        for (int j = 0; j < 4; ++j) acc[i][j] = (f4v){0.f, 0.f, 0.f, 0.f};

    for (int kt = 0; kt < K; kt += 64) {
        if (kt) __syncthreads();
#pragma unroll
        for (int it = 0; it < 4; ++it) {
            int cb = (it * 4 + w) * 64;
            int chunk = cb + lane;
            int r = chunk >> 3;
            int kc = (chunk & 7) << 3;
            gload16(Ab + (size_t)r * lda + kt + kc, &As[cb * 8]);
            gload16(Bb + (size_t)r * ldb + kt + kc, &Bs[cb * 8]);
        }
        __syncthreads();
#pragma unroll
        for (int ks = 0; ks < 2; ++ks) {
            bfrag af[4], bf[4];
#pragma unroll
            for (int i = 0; i < 4; ++i)
                af[i] = *(const bfrag*)&As[(wr * 64 + i * 16 + frow) * 64 + ks * 32 + fk];
#pragma unroll
            for (int j = 0; j < 4; ++j)
                bf[j] = *(const bfrag*)&Bs[(wc * 64 + j * 16 + frow) * 64 + ks * 32 + fk];
#pragma unroll
            for (int i = 0; i < 4; ++i)
#pragma unroll
                for (int j = 0; j < 4; ++j)
                    acc[i][j] = __builtin_amdgcn_mfma_f32_16x16x32_bf16(af[i], bf[j], acc[i][j], 0, 0, 0);
        }
    }

    const int rbase = (lane >> 4) * 4, cbase = lane & 15;

    if (MODE == 0) {
        u16* out1b = out1 + (size_t)z * NP * 128;
        u16* out2b = out2 + (size_t)z * 512 * NP;
#pragma unroll
        for (int i = 0; i < 4; ++i)
#pragma unroll
            for (int j = 0; j < 4; ++j) {
                size_t row0 = m0 + wr * 64 + i * 16 + rbase;
                size_t col = n0 + wc * 64 + j * 16 + cbase;
#pragma unroll
                for (int r = 0; r < 4; ++r) {
                    int o = (int)(row0 + r);
                    float bias = (o < 64) ? bq[o] : (o < 128) ? bk[o - 64] : bv[o - 128];
                    u16 bb = f2bf(acc[i][j][r] + bias);
                    if (o < 128) out1b[col * 128 + o] = bb;
                    else out2b[(size_t)(o - 128) * NP + col] = bb;
                }
            }
    } else {
        float* eb = outF + (size_t)z * ESZ;
        u16* Pb = out1 + (size_t)z * NP * NP;
        float psl[4][4];
#pragma unroll
        for (int i = 0; i < 4; ++i)
#pragma unroll
            for (int r = 0; r < 4; ++r) psl[i][r] = 0.f;
#pragma unroll
        for (int i = 0; i < 4; ++i)
#pragma unroll
            for (int j = 0; j < 4; ++j) {
                size_t row0 = m0 + wr * 64 + i * 16 + rbase;
                size_t col = n0 + wc * 64 + j * 16 + cbase;
#pragma unroll
                for (int r = 0; r < 4; ++r) {
                    float v = acc[i][j][r];
                    size_t ro = row0 + r;
                    float pe = (col < NN) ? __expf(v) : 0.f;
                    if (ro < NN && col < NN) eb[ro * NN + col] = v;
                    Pb[ro * NP + col] = f2bf(pe);
                    psl[i][r] += pe;
                }
            }
        float* pbase = psums + ((size_t)z * 68 + blockIdx.x * 2 + wc) * NP;
#pragma unroll
        for (int i = 0; i < 4; ++i)
#pragma unroll
            for (int r = 0; r < 4; ++r) {
                float s = psl[i][r];
                s += __shfl_xor(s, 1);
                s += __shfl_xor(s, 2);
                s += __shfl_xor(s, 4);
                s += __shfl_xor(s, 8);
                if (cbase == 0)
                    pbase[m0 + wr * 64 + i * 16 + rbase + r] = s;
            }
    }
}

// ---------------- reduce partial sums -> invsum[b][n]
__global__ __launch_bounds__(256) void reduce_sums(const float* __restrict__ psums,
                                                   float* __restrict__ invsum) {
    int idx = blockIdx.x * 256 + threadIdx.x;
    if (idx >= BB * NP) return;
    int b = idx / NP, n = idx % NP;
    const float* p = psums + (size_t)b * 68 * NP + n;
    float s = 0.f;
#pragma unroll
    for (int ct = 0; ct < 68; ++ct) s += p[(size_t)ct * NP];
    invsum[idx] = 1.f / s;
}

// ---------------- PV GEMM: 256x256 tile, 8 waves, 4-phase/K-tile counted-vmcnt pipeline
// ctx partial s: ctxp[s][b][c][n] (bf16) = invsum[n] * sum_{m in s-quarter} V[c][m]*Ptil[n][m]
__global__ __launch_bounds__(512, 2) void gemm_pv8(const u16* __restrict__ Vb,
                                                   const u16* __restrict__ P,
                                                   u16* __restrict__ ctxp,
                                                   const float* __restrict__ invsum) {
    // LDS 128 KB: [buf2][op2][kh2][256 rows][32 k] bf16; each half-unit 16 KB contiguous
    __shared__ u16 lds[65536];

    // 544 blocks = 8 XCDs x 68; n-tile slowest for L2 locality
    unsigned flat = blockIdx.x;
    unsigned wg = (flat & 7u) * 68u + (flat >> 3);
    unsigned ntile = wg / 32u;
    unsigned r = wg - ntile * 32u;
    unsigned mt = r >> 4;            // c-block (0..1)
    unsigned b = (r >> 2) & 3u;      // batch
    unsigned s = r & 3u;             // K split
    const unsigned c0 = mt * 256u, n0 = ntile * 256u;
    const unsigned kbeg = s * (PVNT * 64u);

    const u16* Apan = Vb + (size_t)b * 512 * NP + (size_t)c0 * NP;  // rows = c
    const u16* Bpan = P + (size_t)b * NP * NP + (size_t)n0 * NP;    // rows = n

    const int tid = threadIdx.x;
    const int lane = tid & 63, w = tid >> 6;
    const int wr = w >> 2, wc = w & 3;   // 2M x 4N waves

    // stage one 16KB half-unit (op, k-half kh of K-tile `tile`) into `buf`
    auto stage = [&](int buf, int op, int kh, int tile) {
        const u16* gp = op ? Bpan : Apan;
        unsigned kg = kbeg + (unsigned)tile * 64u + (unsigned)kh * 32u;
        int ubase = ((buf * 2 + op) * 2 + kh) * 8192;   // u16 units
#pragma unroll
        for (int l = 0; l < 2; ++l) {
            int X = (w * 2 + l) * 1024 + lane * 16;     // byte offset within half (per-lane)
            int S = X ^ ((X >> 3) & 0x30);              // inverse swizzle for source
            int row = S >> 6, kb = S & 63;
            const u16* g = gp + (size_t)row * NP + kg + (kb >> 1);
            gload16(g, &lds[ubase + (w * 2 + l) * 512]); // wave-uniform dest
        }
    };
    // read one 16x(8k) fragment: rows rowbase..rowbase+15, k-half ks
    auto rdfrag = [&](int buf, int op, int rowbase, int ks) -> bfrag {
        int row = rowbase + (lane & 15);
        int d = row * 64 + (lane >> 4) * 16;
        d ^= (d >> 3) & 0x30;                            // bank swizzle
        int ubase = ((buf * 2 + op) * 2 + ks) * 8192;
        return *(const bfrag*)((const char*)lds + (size_t)ubase * 2 + d);
    };

    f4v acc[8][4];
#pragma unroll
    for (int i = 0; i < 8; ++i)
#pragma unroll
        for (int j = 0; j < 4; ++j) acc[i][j] = (f4v){0.f, 0.f, 0.f, 0.f};

    // prologue: tile0 fully + tile1 kh0
    stage(0, 0, 0, 0); stage(0, 1, 0, 0);
    stage(0, 0, 1, 0); stage(0, 1, 1, 0);
    stage(1, 0, 0, 1); stage(1, 1, 0, 1);
    asm volatile("s_waitcnt vmcnt(8)" ::: "memory");
    asm volatile("s_barrier" ::: "memory");

    int buf = 0;
#pragma unroll 1
    for (int t = 0; t < PVNT; ++t) {
        const int nb = buf ^ 1;
        bfrag a0, a1, a2, a3, b0, b1, b2, b3;
        // ---- phase 0: rows 0-127 (wr half), k-step 0
        b0 = rdfrag(buf, 1, wc * 64 + 0, 0);  b1 = rdfrag(buf, 1, wc * 64 + 16, 0);
        b2 = rdfrag(buf, 1, wc * 64 + 32, 0); b3 = rdfrag(buf, 1, wc * 64 + 48, 0);
        a0 = rdfrag(buf, 0, wr * 128 + 0, 0);  a1 = rdfrag(buf, 0, wr * 128 + 16, 0);
        a2 = rdfrag(buf, 0, wr * 128 + 32, 0); a3 = rdfrag(buf, 0, wr * 128 + 48, 0);
        if (t + 1 < PVNT) stage(nb, 0, 1, t + 1);
        asm volatile("s_barrier" ::: "memory");
        __builtin_amdgcn_s_setprio(1);
#define MF(i, A, B, j) acc[i][j] = __builtin_amdgcn_mfma_f32_16x16x32_bf16(A, B, acc[i][j], 0, 0, 0)
        MF(0, a0, b0, 0); MF(0, a0, b1, 1); MF(0, a0, b2, 2); MF(0, a0, b3, 3);
        MF(1, a1, b0, 0); MF(1, a1, b1, 1); MF(1, a1, b2, 2); MF(1, a1, b3, 3);
        MF(2, a2, b0, 0); MF(2, a2, b1, 1); MF(2, a2, b2, 2); MF(2, a2, b3, 3);
        MF(3, a3, b0, 0); MF(3, a3, b1, 1); MF(3, a3, b2, 2); MF(3, a3, b3, 3);
        __builtin_amdgcn_s_setprio(0);
        asm volatile("s_barrier" ::: "memory");
        // ---- phase 1: rows 128-255, k-step 0 (b reused)
        a0 = rdfrag(buf, 0, wr * 128 + 64, 0);  a1 = rdfrag(buf, 0, wr * 128 + 80, 0);
        a2 = rdfrag(buf, 0, wr * 128 + 96, 0);  a3 = rdfrag(buf, 0, wr * 128 + 112, 0);
        if (t + 1 < PVNT) stage(nb, 1, 1, t + 1);
        if (t < PVNT - 1) asm volatile("s_waitcnt vmcnt(8)" ::: "memory");
        else              asm volatile("s_waitcnt vmcnt(0)" ::: "memory");
        asm volatile("s_barrier" ::: "memory");
        __builtin_amdgcn_s_setprio(1);
        MF(4, a0, b0, 0); MF(4, a0, b1, 1); MF(4, a0, b2, 2); MF(4, a0, b3, 3);
        MF(5, a1, b0, 0); MF(5, a1, b1, 1); MF(5, a1, b2, 2); MF(5, a1, b3, 3);
        MF(6, a2, b0, 0); MF(6, a2, b1, 1); MF(6, a2, b2, 2); MF(6, a2, b3, 3);
        MF(7, a3, b0, 0); MF(7, a3, b1, 1); MF(7, a3, b2, 2); MF(7, a3, b3, 3);
        __builtin_amdgcn_s_setprio(0);
        asm volatile("s_barrier" ::: "memory");
        // ---- phase 2: rows 0-127, k-step 1
        b0 = rdfrag(buf, 1, wc * 64 + 0, 1);  b1 = rdfrag(buf, 1, wc * 64 + 16, 1);
        b2 = rdfrag(buf, 1, wc * 64 + 32, 1); b3 = rdfrag(buf, 1, wc * 64 + 48, 1);
        a0 = rdfrag(buf, 0, wr * 128 + 0, 1);  a1 = rdfrag(buf, 0, wr * 128 + 16, 1);
        a2 = rdfrag(buf, 0, wr * 128 + 32, 1); a3 = rdfrag(buf, 0, wr * 128 + 48, 1);
        if (t + 2 < PVNT) stage(buf, 0, 0, t + 2);   // cur kh0 freed after phase 1
        asm volatile("s_barrier" ::: "memory");
        __builtin_amdgcn_s_setprio(1);
        MF(0, a0, b0, 0); MF(0, a0, b1, 1); MF(0, a0, b2, 2); MF(0, a0, b3, 3);
        MF(1, a1, b0, 0); MF(1, a1, b1, 1); MF(1, a1, b2, 2); MF(1, a1, b3, 3);
        MF(2, a2, b0, 0); MF(2, a2, b1, 1); MF(2, a2, b2, 2); MF(2, a2, b3, 3);
        MF(3, a3, b0, 0); MF(3, a3, b1, 1); MF(3, a3, b2, 2); MF(3, a3, b3, 3);
        __builtin_amdgcn_s_setprio(0);
        asm volatile("s_barrier" ::: "memory");
        // ---- phase 3: rows 128-255, k-step 1
        a0 = rdfrag(buf, 0, wr * 128 + 64, 1);  a1 = rdfrag(buf, 0, wr * 128 + 80, 1);
        a2 = rdfrag(buf, 0, wr * 128 + 96, 1);  a3 = rdfrag(buf, 0, wr * 128 + 112, 1);
        if (t + 2 < PVNT) stage(buf, 1, 0, t + 2);
        if (t < PVNT - 2)       asm volatile("s_waitcnt vmcnt(8)" ::: "memory");
        else if (t == PVNT - 2) asm volatile("s_waitcnt vmcnt(4)" ::: "memory");
        asm volatile("s_barrier" ::: "memory");
        __builtin_amdgcn_s_setprio(1);
        MF(4, a0, b0, 0); MF(4, a0, b1, 1); MF(4, a0, b2, 2); MF(4, a0, b3, 3);
        MF(5, a1, b0, 0); MF(5, a1, b1, 1); MF(5, a1, b2, 2); MF(5, a1, b3, 3);
        MF(6, a2, b0, 0); MF(6, a2, b1, 1); MF(6, a2, b2, 2); MF(6, a2, b3, 3);
        MF(7, a3, b0, 0); MF(7, a3, b1, 1); MF(7, a3, b2, 2); MF(7, a3, b3, 3);
        __builtin_amdgcn_s_setprio(0);
        asm volatile("s_barrier" ::: "memory");
#undef MF
        buf = nb;
    }

    // epilogue: scale by invsum, write bf16 partial [s][b][c][n]
    const int rbase = (lane >> 4) * 4, cbase = lane & 15;
    u16* cb = ctxp + ((size_t)(s * BB + b) * 512 + c0) * NP;
    const float* isb = invsum + (size_t)b * NP;
#pragma unroll
    for (int j = 0; j < 4; ++j) {
        unsigned n = n0 + wc * 64 + j * 16 + cbase;
        float inv = isb[n];
#pragma unroll
        for (int i = 0; i < 8; ++i) {
            unsigned row = wr * 128 + i * 16 + rbase;
#pragma unroll
            for (int rr = 0; rr < 4; ++rr)
                cb[(size_t)(row + rr) * NP + n] = f2bf(acc[i][j][rr] * inv);
        }
    }
}

// ---------------- upsample: bilinear 2x (exact) + gamma*val + x, summing 4 bf16 partials
#define SLICE ((size_t)BB * 512 * NP)
__global__ __launch_bounds__(256) void upsample_add(const u16* __restrict__ ctxp,
                                                    const float* __restrict__ x,
                                                    const float* __restrict__ gm,
                                                    float* __restrict__ out) {
    unsigned q = blockIdx.x * 256 + threadIdx.x;
    if (q >= (OUTSZ / 4)) return;
    unsigned idx0 = q * 4;
    float g = gm[0];
    float4 xv = *(const float4*)&x[idx0];
    float ov[4];
#pragma unroll
    for (int e = 0; e < 4; ++e) {
        unsigned idx = idx0 + e;
        unsigned xx = idx % WW;
        unsigned t = idx / WW;
        unsigned yy = t % HH;
        unsigned bc = t / HH;
        const u16* cb = ctxp + (size_t)bc * NP;
        unsigned i0 = yy >> 1, j0 = xx >> 1;
        unsigned n00 = i0 * 65 + j0;
        float wy = 0.5f * (float)(yy & 1), wx = 0.5f * (float)(xx & 1);
        float c00 = 0.f, c01 = 0.f, c10 = 0.f, c11 = 0.f;
#pragma unroll
        for (int sl = 0; sl < 4; ++sl) {
            const u16* p = cb + (size_t)sl * SLICE;
            c00 += bf2f(p[n00]);
            c01 += bf2f(p[n00 + 1]);
            c10 += bf2f(p[n00 + 65]);
            c11 += bf2f(p[n00 + 66]);
        }
        float cx0 = c00 + wx * (c01 - c00);
        float cx1 = c10 + wx * (c11 - c10);
        ov[e] = g * (cx0 + wy * (cx1 - cx0));
    }
    float4 o4 = {ov[0] + xv.x, ov[1] + xv.y, ov[2] + xv.z, ov[3] + xv.w};
    *(float4*)&out[idx0] = o4;
}

// ---------------- workspace layout (bytes)
#define SZ_WC    ((size_t)640 * 512 * 2)
#define OFF_XST  (SZ_WC)
#define SZ_XST   ((size_t)BB * NP * 512 * 2)
#define OFF_QKT  (OFF_XST + SZ_XST)
#define SZ_QKT   ((size_t)BB * NP * 128 * 2)
#define OFF_V    (OFF_QKT + SZ_QKT)
#define SZ_V     ((size_t)BB * 512 * NP * 2)
#define OFF_PS   (OFF_V + SZ_V)
#define SZ_PS    ((size_t)BB * 68 * NP * 4)
#define OFF_INV  (OFF_PS + SZ_PS)
#define SZ_INV   ((size_t)BB * NP * 4)
#define OFF_CTXP (OFF_INV + SZ_INV)
#define SZ_CTXP  ((size_t)4 * BB * 512 * NP * 2)
#define OFF_P    (OFF_CTXP + SZ_CTXP)

extern "C" void kernel_launch(void* const* d_in, const int* in_sizes, int n_in,
                              void* d_out, int out_size, void* d_ws, size_t ws_size,
                              hipStream_t stream) {
    const float* x  = (const float*)d_in[0];
    const float* Wq = (const float*)d_in[1];
    const float* bq = (const float*)d_in[2];
    const float* Wk = (const float*)d_in[3];
    const float* bk = (const float*)d_in[4];
    const float* Wv = (const float*)d_in[5];
    const float* bv = (const float*)d_in[6];
    const float* gm = (const float*)d_in[7];

    float* out = (float*)d_out;
    float* energy = out + (size_t)OUTSZ;

    char* ws = (char*)d_ws;
    u16* Wc    = (u16*)(ws);
    u16* XsT   = (u16*)(ws + OFF_XST);
    u16* qkT   = (u16*)(ws + OFF_QKT);
    u16* V     = (u16*)(ws + OFF_V);
    float* psums  = (float*)(ws + OFF_PS);
    float* invsum = (float*)(ws + OFF_INV);
    u16* ctxp  = (u16*)(ws + OFF_CTXP);
    u16* P     = (u16*)(ws + OFF_P);

    cast_weights<<<1280, 256, 0, stream>>>(Wq, Wk, Wv, Wc);
    subsample_t<<<dim3(68, 8, BB), 256, 0, stream>>>(x, XsT);
    gemm_nt<0><<<dim3(34, 5, BB), 256, 0, stream>>>(Wc, XsT, 512, 512, 512,
                                                    nullptr, qkT, V, bq, bk, bv, nullptr);
    gemm_nt<1><<<dim3(34, 34, BB), 256, 0, stream>>>(qkT, qkT, 64, 128, 128,
                                                     energy, P, nullptr, nullptr, nullptr, nullptr,
                                                     psums);
    reduce_sums<<<68, 256, 0, stream>>>(psums, invsum);
    gemm_pv8<<<544, 512, 0, stream>>>(V, P, ctxp, invsum);
    upsample_add<<<(OUTSZ / 4 + 255) / 256, 256, 0, stream>>>(ctxp, x, gm, out);
}

// Round 5
// 460.794 us; speedup vs baseline: 1.0749x; 1.0749x over previous
//
#include <hip/hip_runtime.h>
#include <hip/hip_bf16.h>
#include <cstdint>

// Problem constants
#define BB 4
#define CC 512
#define CQK 64
#define HH 129
#define WW 129
#define HS 65
#define WSZ 65
#define NN 4225            // HS*WSZ
#define NP 4352            // padded N (34*128)
#define KPV 4288           // 67 K-tiles of 64; P cols 4288.. are zero
#define OUTSZ 34080768     // BB*CC*HH*WW
#define ESZ 17850625       // NN*NN

typedef unsigned short u16;
typedef __attribute__((ext_vector_type(8))) __bf16 bfrag;
typedef __attribute__((ext_vector_type(4))) float f4v;

__device__ inline u16 f2bf(float f) {
    union { float f; unsigned int u; } v; v.f = f;
    unsigned int u = v.u;
    return (u16)((u + 0x7FFFu + ((u >> 16) & 1u)) >> 16);
}
__device__ inline float bf2f(u16 v) {
    union { unsigned u; float f; } x; x.u = (unsigned)v << 16; return x.f;
}

// async global->LDS, 16 bytes per lane; lds dest must be wave-uniform base
__device__ __forceinline__ void gload16(const u16* g, u16* l) {
    __builtin_amdgcn_global_load_lds(
        (const __attribute__((address_space(1))) void*)g,
        (__attribute__((address_space(3))) void*)l, 16, 0, 0);
}

// ---------------- K0: cast & pack weights [640][512] bf16
__global__ __launch_bounds__(256) void cast_weights(const float* __restrict__ Wq,
                                                    const float* __restrict__ Wk,
                                                    const float* __restrict__ Wv,
                                                    u16* __restrict__ Wc) {
    int idx = blockIdx.x * 256 + threadIdx.x;
    if (idx >= 640 * 512) return;
    int o = idx >> 9, c = idx & 511;
    float v = (o < 64) ? Wq[o * 512 + c] : (o < 128) ? Wk[(o - 64) * 512 + c] : Wv[(o - 128) * 512 + c];
    Wc[idx] = f2bf(v);
}

// ---------------- K1: subsample (exact stride-2) + transpose to XsT[b][n][c] bf16
__global__ __launch_bounds__(256) void subsample_t(const float* __restrict__ x, u16* __restrict__ XsT) {
    __shared__ u16 tile[64][65];
    int nt = blockIdx.x, ct = blockIdx.y, b = blockIdx.z;
    int t = threadIdx.x;
#pragma unroll
    for (int l = 0; l < 16; ++l) {
        int e = t + l * 256;
        int ci = e >> 6, nj = e & 63;
        int n = nt * 64 + nj;
        int nc = n < (NN - 1) ? n : (NN - 1);
        int i = nc / 65, j = nc % 65;
        int c = ct * 64 + ci;
        float v = x[(((size_t)b * CC + c) * HH + 2 * i) * WW + 2 * j];
        tile[ci][nj] = f2bf(v);
    }
    __syncthreads();
#pragma unroll
    for (int l = 0; l < 16; ++l) {
        int e = t + l * 256;
        int nj = e >> 6, ci = e & 63;
        XsT[((size_t)b * NP + nt * 64 + nj) * 512 + ct * 64 + ci] = tile[ci][nj];
    }
}

// ---------------- NT GEMM (m97 structure) for QKV and energy
// MODE 0: QKV  A=Wc[640][512], B=XsT[b], out -> qkT[n][o] (o<128) / V[o-128][n], +bias, bf16
// MODE 1: energy A=qkT[b] cols0-63 (q), B=qkT[b] cols64-127 (k), K=64,
//         out -> energy fp32 + Ptil bf16 (=exp(e), col-padded 0, LDS-repacked coalesced)
//         + per-row partial sums
template <int MODE>
__global__ __launch_bounds__(256) void gemm_nt(const u16* __restrict__ Abase,
                                               const u16* __restrict__ Bbase,
                                               int K, int lda, int ldb,
                                               float* __restrict__ outF,
                                               u16* __restrict__ out1, u16* __restrict__ out2,
                                               const float* __restrict__ bq,
                                               const float* __restrict__ bk,
                                               const float* __restrict__ bv,
                                               float* __restrict__ psums) {
    __shared__ __align__(16) u16 S[16384];   // As = S[0..8191], Bs = S[8192..]; reused for repack
    u16* As = S;
    u16* Bs = S + 8192;

    const int z = blockIdx.z;
    const u16* A; const u16* Bm;
    if (MODE == 0) { A = Abase;                          Bm = Bbase + (size_t)z * NP * 512; }
    if (MODE == 1) { A = Abase + (size_t)z * NP * 128;   Bm = Bbase + (size_t)z * NP * 128 + 64; }

    const size_t m0 = (size_t)blockIdx.y * 128;
    const size_t n0 = (size_t)blockIdx.x * 128;
    const u16* Ab = A + m0 * lda;
    const u16* Bb = Bm + n0 * ldb;

    const int tid = threadIdx.x;
    const int lane = tid & 63, w = tid >> 6;
    const int wr = w >> 1, wc = w & 1;
    const int frow = lane & 15, fk = (lane >> 4) * 8;

    f4v acc[4][4];
#pragma unroll
    for (int i = 0; i < 4; ++i)
#pragma unroll
        for (int j = 0; j < 4; ++j) acc[i][j] = (f4v){0.f, 0.f, 0.f, 0.f};

    for (int kt = 0; kt < K; kt += 64) {
        if (kt) __syncthreads();
#pragma unroll
        for (int it = 0; it < 4; ++it) {
            int cb = (it * 4 + w) * 64;
            int chunk = cb + lane;
            int r = chunk >> 3;
            int kc = (chunk & 7) << 3;
            gload16(Ab + (size_t)r * lda + kt + kc, &As[cb * 8]);
            gload16(Bb + (size_t)r * ldb + kt + kc, &Bs[cb * 8]);
        }
        __syncthreads();
#pragma unroll
        for (int ks = 0; ks < 2; ++ks) {
            bfrag af[4], bf[4];
#pragma unroll
            for (int i = 0; i < 4; ++i)
                af[i] = *(const bfrag*)&As[(wr * 64 + i * 16 + frow) * 64 + ks * 32 + fk];
#pragma unroll
            for (int j = 0; j < 4; ++j)
                bf[j] = *(const bfrag*)&Bs[(wc * 64 + j * 16 + frow) * 64 + ks * 32 + fk];
#pragma unroll
            for (int i = 0; i < 4; ++i)
#pragma unroll
                for (int j = 0; j < 4; ++j)
                    acc[i][j] = __builtin_amdgcn_mfma_f32_16x16x32_bf16(af[i], bf[j], acc[i][j], 0, 0, 0);
        }
    }

    const int rbase = (lane >> 4) * 4, cbase = lane & 15;

    if (MODE == 0) {
        u16* out1b = out1 + (size_t)z * NP * 128;
        u16* out2b = out2 + (size_t)z * 512 * NP;
#pragma unroll
        for (int i = 0; i < 4; ++i)
#pragma unroll
            for (int j = 0; j < 4; ++j) {
                size_t row0 = m0 + wr * 64 + i * 16 + rbase;
                size_t col = n0 + wc * 64 + j * 16 + cbase;
#pragma unroll
                for (int r = 0; r < 4; ++r) {
                    int o = (int)(row0 + r);
                    float bias = (o < 64) ? bq[o] : (o < 128) ? bk[o - 64] : bv[o - 128];
                    u16 bb = f2bf(acc[i][j][r] + bias);
                    if (o < 128) out1b[col * 128 + o] = bb;
                    else out2b[(size_t)(o - 128) * NP + col] = bb;
                }
            }
    } else {
        float* eb = outF + (size_t)z * ESZ;
        u16* Pb = out1 + (size_t)z * NP * NP;
        float psl[4][4];
#pragma unroll
        for (int i = 0; i < 4; ++i)
#pragma unroll
            for (int r = 0; r < 4; ++r) psl[i][r] = 0.f;

        __syncthreads();   // all waves done reading As/Bs; S is free for repack
#pragma unroll
        for (int i = 0; i < 4; ++i)
#pragma unroll
            for (int j = 0; j < 4; ++j) {
                int rl = wr * 64 + i * 16 + rbase;          // local row 0..127
                int cl = wc * 64 + j * 16 + cbase;          // local col 0..127
                size_t row0 = m0 + rl;
                size_t col = n0 + cl;
#pragma unroll
                for (int r = 0; r < 4; ++r) {
                    float v = acc[i][j][r];
                    size_t ro = row0 + r;
                    float pe = (col < NN) ? __expf(v) : 0.f;
                    if (ro < NN && col < NN) eb[ro * NN + col] = v;
                    S[(rl + r) * 128 + cl] = f2bf(pe);
                    psl[i][r] += pe;
                }
            }
        float* pbase = psums + ((size_t)z * 68 + blockIdx.x * 2 + wc) * NP;
#pragma unroll
        for (int i = 0; i < 4; ++i)
#pragma unroll
            for (int r = 0; r < 4; ++r) {
                float s = psl[i][r];
                s += __shfl_xor(s, 1);
                s += __shfl_xor(s, 2);
                s += __shfl_xor(s, 4);
                s += __shfl_xor(s, 8);
                if (cbase == 0)
                    pbase[m0 + wr * 64 + i * 16 + rbase + r] = s;
            }
        __syncthreads();
        // coalesced P write: 128 rows x 16 int4
        u16* pb = Pb + m0 * NP + n0;
#pragma unroll
        for (int l = 0; l < 8; ++l) {
            int idx = tid + l * 256;
            int row = idx >> 4, c16 = idx & 15;
            *(int4*)(pb + (size_t)row * NP + c16 * 8) = *(const int4*)&S[row * 128 + c16 * 8];
        }
    }
}

// ---------------- reduce partial sums -> invsum[b][n]
__global__ __launch_bounds__(256) void reduce_sums(const float* __restrict__ psums,
                                                   float* __restrict__ invsum) {
    int idx = blockIdx.x * 256 + threadIdx.x;
    if (idx >= BB * NP) return;
    int b = idx / NP, n = idx % NP;
    const float* p = psums + (size_t)b * 68 * NP + n;
    float s = 0.f;
#pragma unroll
    for (int ct = 0; ct < 68; ++ct) s += p[(size_t)ct * NP];
    invsum[idx] = 1.f / s;
}

// ---------------- PV GEMM: split-K x2, bijective XCD swizzle (m-fastest in slice),
// bf16 ctx partials written coalesced via LDS repack.
// ctxp[half][b][c][n] = invsum[n] * sum_{m in half} V[c][m] * Ptil[n][m]
__global__ __launch_bounds__(256) void gemm_pv(const u16* __restrict__ Vb,
                                               const u16* __restrict__ P,
                                               u16* __restrict__ ctxp,
                                               const float* __restrict__ invsum) {
    __shared__ __align__(16) u16 S[16384];
    u16* As = S;
    u16* Bs = S + 8192;

    // grid (34,4,8): nwg = 1088 = 8*136; XCD k gets one contiguous (batch,half) slice.
    // Within a slice: c-tile (ys) fastest, so the 4 blocks sharing a P-panel are adjacent.
    unsigned flat = blockIdx.x + 34u * (blockIdx.y + 4u * blockIdx.z);
    unsigned swz = (flat & 7u) * 136u + (flat >> 3);
    unsigned zs = swz / 136u;
    unsigned rem = swz - zs * 136u;
    unsigned xs = rem >> 2;          // n-tile 0..33
    unsigned ys = rem & 3u;          // c-tile 0..3
    const int b = (int)(zs >> 1), half = (int)(zs & 1);

    const u16* A = Vb + (size_t)b * 512 * NP;
    const u16* Bm = P + (size_t)b * NP * NP;
    const size_t m0 = (size_t)ys * 128;
    const size_t n0 = (size_t)xs * 128;
    const u16* Ab = A + m0 * NP;
    const u16* Bb = Bm + n0 * NP;
    const int kbeg = half ? 2176 : 0;
    const int kend = half ? KPV : 2176;

    const int tid = threadIdx.x;
    const int lane = tid & 63, w = tid >> 6;
    const int wr = w >> 1, wc = w & 1;
    const int frow = lane & 15, fk = (lane >> 4) * 8;

    f4v acc[4][4];
#pragma unroll
    for (int i = 0; i < 4; ++i)
#pragma unroll
        for (int j = 0; j < 4; ++j) acc[i][j] = (f4v){0.f, 0.f, 0.f, 0.f};

    for (int kt = kbeg; kt < kend; kt += 64) {
        if (kt != kbeg) __syncthreads();
#pragma unroll
        for (int it = 0; it < 4; ++it) {
            int cb = (it * 4 + w) * 64;
            int chunk = cb + lane;
            int r = chunk >> 3;
            int kc = (chunk & 7) << 3;
            gload16(Ab + (size_t)r * NP + kt + kc, &As[cb * 8]);
            gload16(Bb + (size_t)r * NP + kt + kc, &Bs[cb * 8]);
        }
        __syncthreads();
#pragma unroll
        for (int ks = 0; ks < 2; ++ks) {
            bfrag af[4], bf[4];
#pragma unroll
            for (int i = 0; i < 4; ++i)
                af[i] = *(const bfrag*)&As[(wr * 64 + i * 16 + frow) * 64 + ks * 32 + fk];
#pragma unroll
            for (int j = 0; j < 4; ++j)
                bf[j] = *(const bfrag*)&Bs[(wc * 64 + j * 16 + frow) * 64 + ks * 32 + fk];
#pragma unroll
            for (int i = 0; i < 4; ++i)
#pragma unroll
                for (int j = 0; j < 4; ++j)
                    acc[i][j] = __builtin_amdgcn_mfma_f32_16x16x32_bf16(af[i], bf[j], acc[i][j], 0, 0, 0);
        }
    }

    // epilogue: scale by invsum, repack bf16 tile in LDS, coalesced int4 store
    const int rbase = (lane >> 4) * 4, cbase = lane & 15;
    const float* isb = invsum + (size_t)b * NP;
    __syncthreads();
#pragma unroll
    for (int j = 0; j < 4; ++j) {
        int cl = wc * 64 + j * 16 + cbase;
        float inv = isb[n0 + cl];
#pragma unroll
        for (int i = 0; i < 4; ++i) {
            int rl = wr * 64 + i * 16 + rbase;
#pragma unroll
            for (int r = 0; r < 4; ++r)
                S[(rl + r) * 128 + cl] = f2bf(acc[i][j][r] * inv);
        }
    }
    __syncthreads();
    u16* cb = ctxp + ((size_t)(half * BB + b) * 512 + m0) * NP + n0;
#pragma unroll
    for (int l = 0; l < 8; ++l) {
        int idx = tid + l * 256;
        int row = idx >> 4, c16 = idx & 15;
        *(int4*)(cb + (size_t)row * NP + c16 * 8) = *(const int4*)&S[row * 128 + c16 * 8];
    }
}

// ---------------- upsample: bilinear 2x (exact) + gamma*val + x, summing 2 bf16 partials
#define SLICE ((size_t)BB * 512 * NP)
__global__ __launch_bounds__(256) void upsample_add(const u16* __restrict__ ctxp,
                                                    const float* __restrict__ x,
                                                    const float* __restrict__ gm,
                                                    float* __restrict__ out) {
    unsigned q = blockIdx.x * 256 + threadIdx.x;
    if (q >= (OUTSZ / 4)) return;
    unsigned idx0 = q * 4;
    float g = gm[0];
    float4 xv = *(const float4*)&x[idx0];
    float ov[4];
#pragma unroll
    for (int e = 0; e < 4; ++e) {
        unsigned idx = idx0 + e;
        unsigned xx = idx % WW;
        unsigned t = idx / WW;
        unsigned yy = t % HH;
        unsigned bc = t / HH;
        const u16* cb = ctxp + (size_t)bc * NP;
        unsigned i0 = yy >> 1, j0 = xx >> 1;
        unsigned n00 = i0 * 65 + j0;
        float wy = 0.5f * (float)(yy & 1), wx = 0.5f * (float)(xx & 1);
        float c00 = 0.f, c01 = 0.f, c10 = 0.f, c11 = 0.f;
#pragma unroll
        for (int sl = 0; sl < 2; ++sl) {
            const u16* p = cb + (size_t)sl * SLICE;
            c00 += bf2f(p[n00]);
            c01 += bf2f(p[n00 + 1]);
            c10 += bf2f(p[n00 + 65]);
            c11 += bf2f(p[n00 + 66]);
        }
        float cx0 = c00 + wx * (c01 - c00);
        float cx1 = c10 + wx * (c11 - c10);
        ov[e] = g * (cx0 + wy * (cx1 - cx0));
    }
    float4 o4 = {ov[0] + xv.x, ov[1] + xv.y, ov[2] + xv.z, ov[3] + xv.w};
    *(float4*)&out[idx0] = o4;
}

// ---------------- workspace layout (bytes)
#define SZ_WC    ((size_t)640 * 512 * 2)
#define OFF_XST  (SZ_WC)
#define SZ_XST   ((size_t)BB * NP * 512 * 2)
#define OFF_QKT  (OFF_XST + SZ_XST)
#define SZ_QKT   ((size_t)BB * NP * 128 * 2)
#define OFF_V    (OFF_QKT + SZ_QKT)
#define SZ_V     ((size_t)BB * 512 * NP * 2)
#define OFF_PS   (OFF_V + SZ_V)
#define SZ_PS    ((size_t)BB * 68 * NP * 4)
#define OFF_INV  (OFF_PS + SZ_PS)
#define SZ_INV   ((size_t)BB * NP * 4)
#define OFF_CTXP (OFF_INV + SZ_INV)
#define SZ_CTXP  ((size_t)2 * BB * 512 * NP * 2)
#define OFF_P    (OFF_CTXP + SZ_CTXP)

extern "C" void kernel_launch(void* const* d_in, const int* in_sizes, int n_in,
                              void* d_out, int out_size, void* d_ws, size_t ws_size,
                              hipStream_t stream) {
    const float* x  = (const float*)d_in[0];
    const float* Wq = (const float*)d_in[1];
    const float* bq = (const float*)d_in[2];
    const float* Wk = (const float*)d_in[3];
    const float* bk = (const float*)d_in[4];
    const float* Wv = (const float*)d_in[5];
    const float* bv = (const float*)d_in[6];
    const float* gm = (const float*)d_in[7];

    float* out = (float*)d_out;
    float* energy = out + (size_t)OUTSZ;

    char* ws = (char*)d_ws;
    u16* Wc    = (u16*)(ws);
    u16* XsT   = (u16*)(ws + OFF_XST);
    u16* qkT   = (u16*)(ws + OFF_QKT);
    u16* V     = (u16*)(ws + OFF_V);
    float* psums  = (float*)(ws + OFF_PS);
    float* invsum = (float*)(ws + OFF_INV);
    u16* ctxp  = (u16*)(ws + OFF_CTXP);
    u16* P     = (u16*)(ws + OFF_P);

    cast_weights<<<1280, 256, 0, stream>>>(Wq, Wk, Wv, Wc);
    subsample_t<<<dim3(68, 8, BB), 256, 0, stream>>>(x, XsT);
    gemm_nt<0><<<dim3(34, 5, BB), 256, 0, stream>>>(Wc, XsT, 512, 512, 512,
                                                    nullptr, qkT, V, bq, bk, bv, nullptr);
    gemm_nt<1><<<dim3(34, 34, BB), 256, 0, stream>>>(qkT, qkT, 64, 128, 128,
                                                     energy, P, nullptr, nullptr, nullptr, nullptr,
                                                     psums);
    reduce_sums<<<68, 256, 0, stream>>>(psums, invsum);
    gemm_pv<<<dim3(34, 4, 8), 256, 0, stream>>>(V, P, ctxp, invsum);
    upsample_add<<<(OUTSZ / 4 + 255) / 256, 256, 0, stream>>>(ctxp, x, gm, out);
}

// Round 6
// 420.292 us; speedup vs baseline: 1.1784x; 1.0964x over previous
//
#include <hip/hip_runtime.h>
#include <hip/hip_bf16.h>
#include <cstdint>

// Problem constants
#define BB 4
#define CC 512
#define CQK 64
#define HH 129
#define WW 129
#define HS 65
#define WSZ 65
#define NN 4225            // HS*WSZ
#define NP 4352            // padded N (34*128)
#define KPV 4288           // 67 K-tiles of 64; P cols 4288.. are zero
#define OUTSZ 34080768     // BB*CC*HH*WW
#define ESZ 17850625       // NN*NN
#define PLANE 16641        // 129*129

typedef unsigned short u16;
typedef __attribute__((ext_vector_type(8))) __bf16 bfrag;
typedef __attribute__((ext_vector_type(4))) float f4v;

__device__ inline u16 f2bf(float f) {
    union { float f; unsigned int u; } v; v.f = f;
    unsigned int u = v.u;
    return (u16)((u + 0x7FFFu + ((u >> 16) & 1u)) >> 16);
}
__device__ inline float bf2f(u16 v) {
    union { unsigned u; float f; } x; x.u = (unsigned)v << 16; return x.f;
}

// async global->LDS, 16 bytes per lane; lds dest must be wave-uniform base
__device__ __forceinline__ void gload16(const u16* g, u16* l) {
    __builtin_amdgcn_global_load_lds(
        (const __attribute__((address_space(1))) void*)g,
        (__attribute__((address_space(3))) void*)l, 16, 0, 0);
}

// ---------------- K0: merged setup — cast weights (blocks 0..1279) + subsample-T (rest)
__global__ __launch_bounds__(256) void setup_k(const float* __restrict__ Wq,
                                               const float* __restrict__ Wk,
                                               const float* __restrict__ Wv,
                                               const float* __restrict__ x,
                                               u16* __restrict__ Wc,
                                               u16* __restrict__ XsT) {
    __shared__ u16 tile[64][65];
    if (blockIdx.x < 1280) {
        int idx = blockIdx.x * 256 + threadIdx.x;
        int o = idx >> 9, c = idx & 511;
        float v = (o < 64) ? Wq[o * 512 + c] : (o < 128) ? Wk[(o - 64) * 512 + c] : Wv[(o - 128) * 512 + c];
        Wc[idx] = f2bf(v);
        return;
    }
    int bid = blockIdx.x - 1280;
    int nt = bid % 68;
    int ct = (bid / 68) & 7;
    int b = bid / 544;
    int t = threadIdx.x;
#pragma unroll
    for (int l = 0; l < 16; ++l) {
        int e = t + l * 256;
        int ci = e >> 6, nj = e & 63;
        int n = nt * 64 + nj;
        int nc = n < (NN - 1) ? n : (NN - 1);
        int i = nc / 65, j = nc % 65;
        int c = ct * 64 + ci;
        float v = x[(((size_t)b * CC + c) * HH + 2 * i) * WW + 2 * j];
        tile[ci][nj] = f2bf(v);
    }
    __syncthreads();
#pragma unroll
    for (int l = 0; l < 16; ++l) {
        int e = t + l * 256;
        int nj = e >> 6, ci = e & 63;
        XsT[((size_t)b * NP + nt * 64 + nj) * 512 + ct * 64 + ci] = tile[ci][nj];
    }
}

// ---------------- NT GEMM (m97 structure) for QKV and energy
// MODE 0: QKV  A=Wc[640][512], B=XsT[b], out -> qkT[n][o] (o<128) / V[o-128][n], +bias, bf16
//         flat grid 680 = 8 XCD slices x (17 n x 5 m, m fastest for B-panel L2 reuse)
// MODE 1: energy A=qkT[b] cols0-63 (q), B=qkT[b] cols64-127 (k), K=64,
//         out -> energy fp32 + Ptil bf16 (exp, col-padded 0, LDS-repacked) + row psums
template <int MODE>
__global__ __launch_bounds__(256) void gemm_nt(const u16* __restrict__ Abase,
                                               const u16* __restrict__ Bbase,
                                               int K, int lda, int ldb,
                                               float* __restrict__ outF,
                                               u16* __restrict__ out1, u16* __restrict__ out2,
                                               const float* __restrict__ bq,
                                               const float* __restrict__ bk,
                                               const float* __restrict__ bv,
                                               float* __restrict__ psums) {
    __shared__ __align__(16) u16 S[16384];   // As | Bs ; reused for repack
    u16* As = S;
    u16* Bs = S + 8192;

    int z; size_t m0, n0; unsigned xsave = 0;
    if (MODE == 0) {
        unsigned flat = blockIdx.x;
        unsigned s = flat & 7u;
        unsigned k = flat >> 3;
        unsigned m = k % 5u;
        unsigned nl = k / 5u;
        z = (int)(s >> 1);
        m0 = (size_t)m * 128;
        n0 = ((size_t)(s & 1u) * 17u + nl) * 128;
    } else {
        z = blockIdx.z;
        m0 = (size_t)blockIdx.y * 128;
        n0 = (size_t)blockIdx.x * 128;
        xsave = blockIdx.x;
    }

    const u16* A; const u16* Bm;
    if (MODE == 0) { A = Abase;                          Bm = Bbase + (size_t)z * NP * 512; }
    if (MODE == 1) { A = Abase + (size_t)z * NP * 128;   Bm = Bbase + (size_t)z * NP * 128 + 64; }

    const u16* Ab = A + m0 * lda;
    const u16* Bb = Bm + n0 * ldb;

    const int tid = threadIdx.x;
    const int lane = tid & 63, w = tid >> 6;
    const int wr = w >> 1, wc = w & 1;
    const int frow = lane & 15, fk = (lane >> 4) * 8;

    f4v acc[4][4];
#pragma unroll
    for (int i = 0; i < 4; ++i)
#pragma unroll
        for (int j = 0; j < 4; ++j) acc[i][j] = (f4v){0.f, 0.f, 0.f, 0.f};

    for (int kt = 0; kt < K; kt += 64) {
        if (kt) __syncthreads();
#pragma unroll
        for (int it = 0; it < 4; ++it) {
            int cb = (it * 4 + w) * 64;
            int chunk = cb + lane;
            int r = chunk >> 3;
            int kc = (chunk & 7) << 3;
            gload16(Ab + (size_t)r * lda + kt + kc, &As[cb * 8]);
            gload16(Bb + (size_t)r * ldb + kt + kc, &Bs[cb * 8]);
        }
        __syncthreads();
#pragma unroll
        for (int ks = 0; ks < 2; ++ks) {
            bfrag af[4], bf[4];
#pragma unroll
            for (int i = 0; i < 4; ++i)
                af[i] = *(const bfrag*)&As[(wr * 64 + i * 16 + frow) * 64 + ks * 32 + fk];
#pragma unroll
            for (int j = 0; j < 4; ++j)
                bf[j] = *(const bfrag*)&Bs[(wc * 64 + j * 16 + frow) * 64 + ks * 32 + fk];
#pragma unroll
            for (int i = 0; i < 4; ++i)
#pragma unroll
                for (int j = 0; j < 4; ++j)
                    acc[i][j] = __builtin_amdgcn_mfma_f32_16x16x32_bf16(af[i], bf[j], acc[i][j], 0, 0, 0);
        }
    }

    const int rbase = (lane >> 4) * 4, cbase = lane & 15;

    if (MODE == 0) {
        u16* out1b = out1 + (size_t)z * NP * 128;
        u16* out2b = out2 + (size_t)z * 512 * NP;
#pragma unroll
        for (int i = 0; i < 4; ++i)
#pragma unroll
            for (int j = 0; j < 4; ++j) {
                size_t row0 = m0 + wr * 64 + i * 16 + rbase;
                size_t col = n0 + wc * 64 + j * 16 + cbase;
#pragma unroll
                for (int r = 0; r < 4; ++r) {
                    int o = (int)(row0 + r);
                    float bias = (o < 64) ? bq[o] : (o < 128) ? bk[o - 64] : bv[o - 128];
                    u16 bb = f2bf(acc[i][j][r] + bias);
                    if (o < 128) out1b[col * 128 + o] = bb;
                    else out2b[(size_t)(o - 128) * NP + col] = bb;
                }
            }
    } else {
        float* eb = outF + (size_t)z * ESZ;
        u16* Pb = out1 + (size_t)z * NP * NP;
        float psl[4][4];
#pragma unroll
        for (int i = 0; i < 4; ++i)
#pragma unroll
            for (int r = 0; r < 4; ++r) psl[i][r] = 0.f;

        __syncthreads();   // all waves done reading As/Bs; S free for repack
#pragma unroll
        for (int i = 0; i < 4; ++i)
#pragma unroll
            for (int j = 0; j < 4; ++j) {
                int rl = wr * 64 + i * 16 + rbase;
                int cl = wc * 64 + j * 16 + cbase;
                size_t row0 = m0 + rl;
                size_t col = n0 + cl;
#pragma unroll
                for (int r = 0; r < 4; ++r) {
                    float v = acc[i][j][r];
                    size_t ro = row0 + r;
                    float pe = (col < NN) ? __expf(v) : 0.f;
                    if (ro < NN && col < NN) eb[ro * NN + col] = v;
                    S[(rl + r) * 128 + cl] = f2bf(pe);
                    psl[i][r] += pe;
                }
            }
        float* pbase = psums + ((size_t)z * 68 + xsave * 2 + wc) * NP;
#pragma unroll
        for (int i = 0; i < 4; ++i)
#pragma unroll
            for (int r = 0; r < 4; ++r) {
                float s = psl[i][r];
                s += __shfl_xor(s, 1);
                s += __shfl_xor(s, 2);
                s += __shfl_xor(s, 4);
                s += __shfl_xor(s, 8);
                if (cbase == 0)
                    pbase[m0 + wr * 64 + i * 16 + rbase + r] = s;
            }
        __syncthreads();
        u16* pb = Pb + m0 * NP + n0;
#pragma unroll
        for (int l = 0; l < 8; ++l) {
            int idx = tid + l * 256;
            int row = idx >> 4, c16 = idx & 15;
            *(int4*)(pb + (size_t)row * NP + c16 * 8) = *(const int4*)&S[row * 128 + c16 * 8];
        }
    }
}

// ---------------- reduce partial sums -> invsum[b][n]
__global__ __launch_bounds__(256) void reduce_sums(const float* __restrict__ psums,
                                                   float* __restrict__ invsum) {
    int idx = blockIdx.x * 256 + threadIdx.x;
    if (idx >= BB * NP) return;
    int b = idx / NP, n = idx % NP;
    const float* p = psums + (size_t)b * 68 * NP + n;
    float s = 0.f;
#pragma unroll
    for (int ct = 0; ct < 68; ++ct) s += p[(size_t)ct * NP];
    invsum[idx] = 1.f / s;
}

// ---------------- PV GEMM: split-K x2, bijective XCD swizzle (c-fastest in slice),
// bf16 ctx partials written coalesced via LDS repack.
__global__ __launch_bounds__(256) void gemm_pv(const u16* __restrict__ Vb,
                                               const u16* __restrict__ P,
                                               u16* __restrict__ ctxp,
                                               const float* __restrict__ invsum) {
    __shared__ __align__(16) u16 S[16384];
    u16* As = S;
    u16* Bs = S + 8192;

    unsigned flat = blockIdx.x + 34u * (blockIdx.y + 4u * blockIdx.z);
    unsigned swz = (flat & 7u) * 136u + (flat >> 3);
    unsigned zs = swz / 136u;
    unsigned rem = swz - zs * 136u;
    unsigned xs = rem >> 2;          // n-tile 0..33
    unsigned ys = rem & 3u;          // c-tile 0..3
    const int b = (int)(zs >> 1), half = (int)(zs & 1);

    const u16* A = Vb + (size_t)b * 512 * NP;
    const u16* Bm = P + (size_t)b * NP * NP;
    const size_t m0 = (size_t)ys * 128;
    const size_t n0 = (size_t)xs * 128;
    const u16* Ab = A + m0 * NP;
    const u16* Bb = Bm + n0 * NP;
    const int kbeg = half ? 2176 : 0;
    const int kend = half ? KPV : 2176;

    const int tid = threadIdx.x;
    const int lane = tid & 63, w = tid >> 6;
    const int wr = w >> 1, wc = w & 1;
    const int frow = lane & 15, fk = (lane >> 4) * 8;

    f4v acc[4][4];
#pragma unroll
    for (int i = 0; i < 4; ++i)
#pragma unroll
        for (int j = 0; j < 4; ++j) acc[i][j] = (f4v){0.f, 0.f, 0.f, 0.f};

    for (int kt = kbeg; kt < kend; kt += 64) {
        if (kt != kbeg) __syncthreads();
#pragma unroll
        for (int it = 0; it < 4; ++it) {
            int cb = (it * 4 + w) * 64;
            int chunk = cb + lane;
            int r = chunk >> 3;
            int kc = (chunk & 7) << 3;
            gload16(Ab + (size_t)r * NP + kt + kc, &As[cb * 8]);
            gload16(Bb + (size_t)r * NP + kt + kc, &Bs[cb * 8]);
        }
        __syncthreads();
#pragma unroll
        for (int ks = 0; ks < 2; ++ks) {
            bfrag af[4], bf[4];
#pragma unroll
            for (int i = 0; i < 4; ++i)
                af[i] = *(const bfrag*)&As[(wr * 64 + i * 16 + frow) * 64 + ks * 32 + fk];
#pragma unroll
            for (int j = 0; j < 4; ++j)
                bf[j] = *(const bfrag*)&Bs[(wc * 64 + j * 16 + frow) * 64 + ks * 32 + fk];
#pragma unroll
            for (int i = 0; i < 4; ++i)
#pragma unroll
                for (int j = 0; j < 4; ++j)
                    acc[i][j] = __builtin_amdgcn_mfma_f32_16x16x32_bf16(af[i], bf[j], acc[i][j], 0, 0, 0);
        }
    }

    const int rbase = (lane >> 4) * 4, cbase = lane & 15;
    const float* isb = invsum + (size_t)b * NP;
    __syncthreads();
#pragma unroll
    for (int j = 0; j < 4; ++j) {
        int cl = wc * 64 + j * 16 + cbase;
        float inv = isb[n0 + cl];
#pragma unroll
        for (int i = 0; i < 4; ++i) {
            int rl = wr * 64 + i * 16 + rbase;
#pragma unroll
            for (int r = 0; r < 4; ++r)
                S[(rl + r) * 128 + cl] = f2bf(acc[i][j][r] * inv);
        }
    }
    __syncthreads();
    u16* cb = ctxp + ((size_t)(half * BB + b) * 512 + m0) * NP + n0;
#pragma unroll
    for (int l = 0; l < 8; ++l) {
        int idx = tid + l * 256;
        int row = idx >> 4, c16 = idx & 15;
        *(int4*)(cb + (size_t)row * NP + c16 * 8) = *(const int4*)&S[row * 128 + c16 * 8];
    }
}

// ---------------- upsample: per-(b,c)-plane, ctx staged in LDS, bilinear 2x + residual
#define SLICE ((size_t)BB * 512 * NP)
__global__ __launch_bounds__(256) void upsample_add(const u16* __restrict__ ctxp,
                                                    const float* __restrict__ x,
                                                    const float* __restrict__ gm,
                                                    float* __restrict__ out) {
    __shared__ float cs[66 * 66];
    const int bc = blockIdx.x;                 // 0..2047 (b*512+c)
    const u16* p0 = ctxp + (size_t)bc * NP;
    const u16* p1 = p0 + SLICE;
    const int t = threadIdx.x;

    for (int idx = t; idx < 4225; idx += 256) {
        int r = idx / 65, c = idx - r * 65;
        cs[r * 66 + c] = bf2f(p0[idx]) + bf2f(p1[idx]);
    }
    if (t < 66) cs[t * 66 + 65] = 0.f;                 // weight-0 pads, keep finite
    if (t >= 128 && t < 193) cs[65 * 66 + (t - 128)] = 0.f;
    __syncthreads();

    const float g = gm[0];
    const float* xb = x + (size_t)bc * PLANE;
    float* ob = out + (size_t)bc * PLANE;
    for (int idx = t; idx < PLANE; idx += 256) {
        int yy = idx / 129, xx = idx - yy * 129;
        int i0 = yy >> 1, j0 = xx >> 1;
        float wy = 0.5f * (float)(yy & 1), wx = 0.5f * (float)(xx & 1);
        const float* c0 = &cs[i0 * 66 + j0];
        float c00 = c0[0], c01 = c0[1], c10 = c0[66], c11 = c0[67];
        float cx0 = c00 + wx * (c01 - c00);
        float cx1 = c10 + wx * (c11 - c10);
        ob[idx] = g * (cx0 + wy * (cx1 - cx0)) + xb[idx];
    }
}

// ---------------- workspace layout (bytes)
#define SZ_WC    ((size_t)640 * 512 * 2)
#define OFF_XST  (SZ_WC)
#define SZ_XST   ((size_t)BB * NP * 512 * 2)
#define OFF_QKT  (OFF_XST + SZ_XST)
#define SZ_QKT   ((size_t)BB * NP * 128 * 2)
#define OFF_V    (OFF_QKT + SZ_QKT)
#define SZ_V     ((size_t)BB * 512 * NP * 2)
#define OFF_PS   (OFF_V + SZ_V)
#define SZ_PS    ((size_t)BB * 68 * NP * 4)
#define OFF_INV  (OFF_PS + SZ_PS)
#define SZ_INV   ((size_t)BB * NP * 4)
#define OFF_CTXP (OFF_INV + SZ_INV)
#define SZ_CTXP  ((size_t)2 * BB * 512 * NP * 2)
#define OFF_P    (OFF_CTXP + SZ_CTXP)

extern "C" void kernel_launch(void* const* d_in, const int* in_sizes, int n_in,
                              void* d_out, int out_size, void* d_ws, size_t ws_size,
                              hipStream_t stream) {
    const float* x  = (const float*)d_in[0];
    const float* Wq = (const float*)d_in[1];
    const float* bq = (const float*)d_in[2];
    const float* Wk = (const float*)d_in[3];
    const float* bk = (const float*)d_in[4];
    const float* Wv = (const float*)d_in[5];
    const float* bv = (const float*)d_in[6];
    const float* gm = (const float*)d_in[7];

    float* out = (float*)d_out;
    float* energy = out + (size_t)OUTSZ;

    char* ws = (char*)d_ws;
    u16* Wc    = (u16*)(ws);
    u16* XsT   = (u16*)(ws + OFF_XST);
    u16* qkT   = (u16*)(ws + OFF_QKT);
    u16* V     = (u16*)(ws + OFF_V);
    float* psums  = (float*)(ws + OFF_PS);
    float* invsum = (float*)(ws + OFF_INV);
    u16* ctxp  = (u16*)(ws + OFF_CTXP);
    u16* P     = (u16*)(ws + OFF_P);

    setup_k<<<3456, 256, 0, stream>>>(Wq, Wk, Wv, x, Wc, XsT);
    gemm_nt<0><<<680, 256, 0, stream>>>(Wc, XsT, 512, 512, 512,
                                        nullptr, qkT, V, bq, bk, bv, nullptr);
    gemm_nt<1><<<dim3(34, 34, BB), 256, 0, stream>>>(qkT, qkT, 64, 128, 128,
                                                     energy, P, nullptr, nullptr, nullptr, nullptr,
                                                     psums);
    reduce_sums<<<68, 256, 0, stream>>>(psums, invsum);
    gemm_pv<<<dim3(34, 4, 8), 256, 0, stream>>>(V, P, ctxp, invsum);
    upsample_add<<<2048, 256, 0, stream>>>(ctxp, x, gm, out);
}